// Round 12
// baseline (257.063 us; speedup 1.0000x reference)
//
#include <hip/hip_runtime.h>
#include <hip/hip_bf16.h>

using f16x8 = __attribute__((ext_vector_type(8))) _Float16;
using f32x4 = __attribute__((ext_vector_type(4))) float;
using fp16x2 = __attribute__((ext_vector_type(2))) __fp16;   // cvt_pkrtz return type

extern "C" __device__ float __ocml_native_exp2_f32(float);

static constexpr int Bc = 4, Sc = 4096, INc = 1024, Nc = 1024, OUTc = 1024;
static constexpr int Mc = Bc * Sc;               // 16384
#define K2LE 2.8853900817779268f                 // 2 * log2(e)

__device__ __forceinline__ unsigned short f2h(float f) {
    return __builtin_bit_cast(unsigned short, (_Float16)f);
}
__device__ __forceinline__ float h2f(unsigned short s) {
    return (float)__builtin_bit_cast(_Float16, s);
}

// ---------------- transpose + f16 convert, both weights in one launch ----------------
// z=0: WiT[c][r] = f16(Wi[r][c]);  z=1: WoT[c][r] = f16(Wo[r][c]). All dims 1024.
__global__ __launch_bounds__(256) void tr_h2(const float* __restrict__ Wi,
                                             const float* __restrict__ Wo,
                                             unsigned short* __restrict__ WiT,
                                             unsigned short* __restrict__ WoT) {
    __shared__ float t[32][33];
    const float* in = blockIdx.z ? Wo : Wi;
    unsigned short* out = blockIdx.z ? WoT : WiT;
    int c0 = blockIdx.x * 32, r0 = blockIdx.y * 32;
    for (int i = threadIdx.y; i < 32; i += 8)
        t[i][threadIdx.x] = in[(size_t)(r0 + i) * 1024 + c0 + threadIdx.x];
    __syncthreads();
    for (int i = threadIdx.y; i < 32; i += 8)
        out[(size_t)(c0 + i) * 1024 + r0 + threadIdx.x] = f2h(t[threadIdx.x][i]);
}

// ---------------- f16 MFMA GEMM: C[M,N] fp32 = A[M,K] * BT[N,K]^T ----------------
// MODE 0: A = f16 array via global_load_lds; no epilogue (GEMM2).
// MODE 1: A = fp32 x staged RAW via global_load_lds (async, zero stage-VALU —
//         same proven m97 shape as MODE 0); the f16 hi/lo split happens at
//         fragment-read time in the COMPUTE phase (overlaps MFMA/ds_read).
//         Split values are bit-identical to R11: hi = pkrtz(x),
//         lo = pkrtz(x - hi); 2 MFMA passes; epilogue C = K2LE*(acc+bi+hs*u+w).
// Both: XCD-chunked blockIdx swizzle (grid % 8 == 0).
template<int MODE>
__global__ __launch_bounds__(256) void gemm_h(const unsigned short* __restrict__ Ah16,
                                              const float* __restrict__ Af32,
                                              const unsigned short* __restrict__ BT,
                                              float* __restrict__ C, int N, int K,
                                              const float* __restrict__ bi,
                                              const float* __restrict__ u,
                                              const float* __restrict__ hs,
                                              const float* __restrict__ wv) {
    constexpr int BM = 128, BN = 128, BK = 64;
    __shared__ alignas(16) float Asf[MODE ? BM * BK : 1];          // 32 KiB (MODE 1)
    __shared__ alignas(16) unsigned short Ash[MODE ? 1 : BM * BK]; // 16 KiB (MODE 0)
    __shared__ alignas(16) unsigned short Bs[BN * BK];             // 16 KiB
    const int nb = N >> 7;
    // T1: XCD-chunked swizzle — consecutive logical tiles land on the same XCD L2.
    const int cpx = (int)gridDim.x >> 3;
    const int wg = (blockIdx.x & 7) * cpx + (blockIdx.x >> 3);
    const int bm = wg / nb, bn = wg % nb;
    const int tid = threadIdx.x;
    const int w = tid >> 6, l = tid & 63;
    const int wr = w >> 1, wc = w & 1;
    const int r = l & 15, g4 = l >> 4;
    const int lrow = l >> 3, lcol = (l & 7) * 8;

    f32x4 acc[4][4] = {};

    const size_t boff = (size_t)bn * BN * K;
    const float* Ab = MODE ? Af32 + (size_t)bm * BM * K : nullptr;

    for (int k0 = 0; k0 < K; k0 += BK) {
        __syncthreads();
        // B staging: global_load_lds direct (unchanged).
#pragma unroll
        for (int i = 0; i < 4; i++) {
            size_t grow = (size_t)((w * 4 + i) * 8 + lrow) * K + (k0 + lcol);
            int ldst = (w * 4 + i) * 512;
            __builtin_amdgcn_global_load_lds(
                (const __attribute__((address_space(1))) void*)(BT + boff + grow),
                (__attribute__((address_space(3))) void*)(Bs + ldst), 16, 0, 0);
        }
        if (MODE) {
            // A staging: RAW fp32 via global_load_lds. Wave w owns rows
            // [w*32, w*32+32); instr i covers 4 rows (lane: row += l>>4,
            // 16B col chunk = l&15). Dest is wave-uniform base + lane*16.
#pragma unroll
            for (int i = 0; i < 8; i++) {
                int row0 = w * 32 + i * 4;
                size_t g = (size_t)(row0 + (l >> 4)) * K + k0 + (l & 15) * 4;
                __builtin_amdgcn_global_load_lds(
                    (const __attribute__((address_space(1))) void*)(Ab + g),
                    (__attribute__((address_space(3))) void*)(Asf + row0 * BK), 16, 0, 0);
            }
        } else {
            const size_t aoff = (size_t)bm * BM * K;
#pragma unroll
            for (int i = 0; i < 4; i++) {
                size_t grow = (size_t)((w * 4 + i) * 8 + lrow) * K + (k0 + lcol);
                __builtin_amdgcn_global_load_lds(
                    (const __attribute__((address_space(1))) void*)(Ah16 + aoff + grow),
                    (__attribute__((address_space(3))) void*)(Ash + (w * 4 + i) * 512), 16, 0, 0);
            }
        }
        __syncthreads();
#pragma unroll
        for (int kk = 0; kk < BK; kk += 32) {
            f16x8 ah[4], al[4], bf[4];
#pragma unroll
            for (int m = 0; m < 4; m++) {
                if (MODE) {
                    // Fragment read + in-register hi/lo split (compute phase:
                    // overlaps MFMA issue and ds_read latency).
                    const float* ap = Asf + (wr * 64 + m * 16 + r) * BK + kk + g4 * 8;
                    float4 a0 = *reinterpret_cast<const float4*>(ap);
                    float4 a1 = *reinterpret_cast<const float4*>(ap + 4);
                    fp16x2 h01 = __builtin_amdgcn_cvt_pkrtz(a0.x, a0.y);
                    fp16x2 h23 = __builtin_amdgcn_cvt_pkrtz(a0.z, a0.w);
                    fp16x2 h45 = __builtin_amdgcn_cvt_pkrtz(a1.x, a1.y);
                    fp16x2 h67 = __builtin_amdgcn_cvt_pkrtz(a1.z, a1.w);
                    fp16x2 l01 = __builtin_amdgcn_cvt_pkrtz(a0.x - (float)h01[0], a0.y - (float)h01[1]);
                    fp16x2 l23 = __builtin_amdgcn_cvt_pkrtz(a0.z - (float)h23[0], a0.w - (float)h23[1]);
                    fp16x2 l45 = __builtin_amdgcn_cvt_pkrtz(a1.x - (float)h45[0], a1.y - (float)h45[1]);
                    fp16x2 l67 = __builtin_amdgcn_cvt_pkrtz(a1.z - (float)h67[0], a1.w - (float)h67[1]);
                    uint4 hu = { __builtin_bit_cast(unsigned int, h01),
                                 __builtin_bit_cast(unsigned int, h23),
                                 __builtin_bit_cast(unsigned int, h45),
                                 __builtin_bit_cast(unsigned int, h67) };
                    uint4 lu = { __builtin_bit_cast(unsigned int, l01),
                                 __builtin_bit_cast(unsigned int, l23),
                                 __builtin_bit_cast(unsigned int, l45),
                                 __builtin_bit_cast(unsigned int, l67) };
                    ah[m] = __builtin_bit_cast(f16x8, hu);
                    al[m] = __builtin_bit_cast(f16x8, lu);
                } else {
                    int off = (wr * 64 + m * 16 + r) * BK + kk + g4 * 8;
                    ah[m] = *reinterpret_cast<const f16x8*>(Ash + off);
                }
            }
#pragma unroll
            for (int n = 0; n < 4; n++)
                bf[n] = *reinterpret_cast<const f16x8*>(Bs + (wc * 64 + n * 16 + r) * BK + kk + g4 * 8);
#pragma unroll
            for (int m = 0; m < 4; m++)
#pragma unroll
                for (int n = 0; n < 4; n++) {
                    acc[m][n] = __builtin_amdgcn_mfma_f32_16x16x32_f16(ah[m], bf[n], acc[m][n], 0, 0, 0);
                    if (MODE)
                        acc[m][n] = __builtin_amdgcn_mfma_f32_16x16x32_f16(al[m], bf[n], acc[m][n], 0, 0, 0);
                }
        }
    }

    const int bbase = MODE ? ((bm * BM) / Sc) * Nc : 0;   // batch uniform per block
#pragma unroll
    for (int m = 0; m < 4; m++) {
        int row = bm * BM + wr * 64 + m * 16 + g4 * 4;
#pragma unroll
        for (int n = 0; n < 4; n++) {
            int col = bn * BN + wc * 64 + n * 16 + r;
            float extra = 0.f;
            if (MODE) extra = bi[col] + hs[bbase + col] * u[col] + wv[col];
#pragma unroll
            for (int q = 0; q < 4; q++) {
                float v = acc[m][n][q];
                if (MODE) v = (v + extra) * K2LE;
                C[(size_t)(row + q) * N + col] = v;
            }
        }
    }
}

// ---------------- sequential tanh recurrence: producer-consumer waves ----------------
// PROVEN (round 5/8: 100 µs, absmax 0.07421875). Scan wall-time = S x chain
// latency (fma->v_exp->add->v_rcp ~52-58 cy) — a serial floor; parallelism
// cannot reduce it (round 6/7 lessons). Wave 0 (producer): per step
// z = fma(nw2, rr, x); e = exp2(z); rr = rcp(e+1); ds_write_b32 rr.
// Wave 1 (consumer): per 32-step chunk, reads rr from LDS, h = 1-2rr, packs
// f16, coalesced dwordx4 stores. Double-buffered LDS; lgkmcnt-only fence on
// wave 0 so the x-prefetch VMEM queue is NEVER drained.
static constexpr int SROW = 68;   // floats per LDS row (64 + 4 pad, 16B-aligned)

template<bool PREF>
__device__ __forceinline__ void sblk(const float* __restrict__ xrow,
                                     float (&cur)[32], float (&nxt)[32],
                                     float* __restrict__ hbl, int tblk, float nw2, float& rr) {
#pragma unroll
    for (int d = 0; d < 32; d++) {
        if (PREF) nxt[d] = xrow[(size_t)(tblk + 32 + d) << 10];   // 1 chunk ahead
        float z = fmaf(nw2, rr, cur[d]);
        float e = __ocml_native_exp2_f32(z);          // v_exp_f32
        rr = __builtin_amdgcn_rcpf(e + 1.f);          // v_rcp_f32
        hbl[d * SROW] = rr;                            // ds_write_b32, imm offset
    }
    asm volatile("s_waitcnt lgkmcnt(0)" ::: "memory");
    __builtin_amdgcn_s_barrier();
}

__device__ __forceinline__ unsigned int pk2(float a, float b) {
    return ((unsigned int)f2h(fmaf(-2.f, b, 1.f)) << 16) | f2h(fmaf(-2.f, a, 1.f));
}

__device__ __forceinline__ void drain(const float* __restrict__ buf, int tblk,
                                      unsigned short* __restrict__ srow, int n0, int l) {
    __builtin_amdgcn_s_barrier();
    asm volatile("" ::: "memory");
    int row8 = l >> 3, cg = l & 7;
#pragma unroll
    for (int i = 0; i < 4; i++) {
        int row = i * 8 + row8;
        float4 a = *reinterpret_cast<const float4*>(&buf[row * SROW + cg * 8]);
        float4 b = *reinterpret_cast<const float4*>(&buf[row * SROW + cg * 8 + 4]);
        uint4 v = { pk2(a.x, a.y), pk2(a.z, a.w), pk2(b.x, b.y), pk2(b.z, b.w) };
        *reinterpret_cast<uint4*>(&srow[((size_t)(tblk + row) << 10) + n0 + cg * 8]) = v;
    }
}

__global__ __launch_bounds__(128) void scan4(const float* __restrict__ xp,
                                             const float* __restrict__ w,
                                             const float* __restrict__ h0,
                                             unsigned short* __restrict__ states,
                                             float* __restrict__ out_state) {
    __shared__ alignas(16) float hb[2][32 * SROW];     // 17 KiB
    const int l = threadIdx.x & 63;
    const int wave = threadIdx.x >> 6;
    const int b = blockIdx.x >> 4;
    const int n0 = (blockIdx.x & 15) * 64;

    if (wave == 0) {
        const int tid = blockIdx.x * 64 + l;           // b*1024 + n
        const int n = tid & (Nc - 1);
        float nw2 = w[n] * (-2.f * K2LE);
        float rr = 0.5f - 0.5f * h0[tid];              // h = 1 - 2*rr
        const float* xrow = xp + ((size_t)b << 22) + n;
        float* hbl0 = &hb[0][l];
        float* hbl1 = &hb[1][l];

        float xa[32], xb[32];
#pragma unroll
        for (int d = 0; d < 32; d++) xa[d] = xrow[(size_t)d << 10];

        int t = 0;
        for (; t + 64 < Sc; t += 64) {
            sblk<true>(xrow, xa, xb, hbl0, t, nw2, rr);
            sblk<true>(xrow, xb, xa, hbl1, t + 32, nw2, rr);
        }
        sblk<true >(xrow, xa, xb, hbl0, t, nw2, rr);
        sblk<false>(xrow, xb, xa, hbl1, t + 32, nw2, rr);
        out_state[tid] = fmaf(-2.f, rr, 1.f);
    } else {
        unsigned short* srow = states + ((size_t)b << 22);
        for (int t = 0; t < Sc; t += 64) {
            drain(hb[0], t, srow, n0, l);
            drain(hb[1], t + 32, srow, n0, l);
        }
    }
}

extern "C" void kernel_launch(void* const* d_in, const int* in_sizes, int n_in,
                              void* d_out, int out_size, void* d_ws, size_t ws_size,
                              hipStream_t stream) {
    const float* x  = (const float*)d_in[0];
    const float* Wi = (const float*)d_in[1];
    const float* bi = (const float*)d_in[2];
    const float* w  = (const float*)d_in[3];
    const float* u  = (const float*)d_in[4];
    const float* Wo = (const float*)d_in[5];
    const float* h0 = (const float*)d_in[6];
    const float* hs = (const float*)d_in[7];
    float* out = (float*)d_out;                          // [M, OUT] fp32
    float* out_state = out + (size_t)Mc * OUTc;          // [B, N] fp32
    float* xp = out;                                     // xp scratch lives in d_out (dead before GEMM2)

    // ws layout (36 MiB): states (f16) 32M | WiT 2M | WoT 2M
    char* ws = (char*)d_ws;
    unsigned short* states = (unsigned short*)ws;
    unsigned short* WiT = (unsigned short*)(ws + 33554432);
    unsigned short* WoT = (unsigned short*)(ws + 35651584);

    tr_h2<<<dim3(32, 32, 2), dim3(32, 8), 0, stream>>>(Wi, Wo, WiT, WoT);

    gemm_h<1><<<(Mc / 128) * (Nc / 128), 256, 0, stream>>>(nullptr, x, WiT, xp, Nc, INc, bi, u, hs, w);
    scan4<<<64, 128, 0, stream>>>(xp, w, h0, states, out_state);
    gemm_h<0><<<(Mc / 128) * (OUTc / 128), 256, 0, stream>>>(states, nullptr, WoT, out, OUTc, Nc,
                                                             nullptr, nullptr, nullptr, nullptr);
}

// Round 13
// 246.069 us; speedup vs baseline: 1.0447x; 1.0447x over previous
//
#include <hip/hip_runtime.h>
#include <hip/hip_bf16.h>

using f16x8 = __attribute__((ext_vector_type(8))) _Float16;
using f32x4 = __attribute__((ext_vector_type(4))) float;
using fp16x2 = __attribute__((ext_vector_type(2))) __fp16;   // cvt_pkrtz return type

extern "C" __device__ float __ocml_native_exp2_f32(float);

static constexpr int Bc = 4, Sc = 4096, INc = 1024, Nc = 1024, OUTc = 1024;
static constexpr int Mc = Bc * Sc;               // 16384
#define K2LE 2.8853900817779268f                 // 2 * log2(e)

__device__ __forceinline__ unsigned short f2h(float f) {
    return __builtin_bit_cast(unsigned short, (_Float16)f);
}
__device__ __forceinline__ float h2f(unsigned short s) {
    return (float)__builtin_bit_cast(_Float16, s);
}

// ---------------- transpose + f16 convert, both weights in one launch ----------------
// z=0: WiT[c][r] = f16(Wi[r][c]);  z=1: WoT[c][r] = f16(Wo[r][c]). All dims 1024.
__global__ __launch_bounds__(256) void tr_h2(const float* __restrict__ Wi,
                                             const float* __restrict__ Wo,
                                             unsigned short* __restrict__ WiT,
                                             unsigned short* __restrict__ WoT) {
    __shared__ float t[32][33];
    const float* in = blockIdx.z ? Wo : Wi;
    unsigned short* out = blockIdx.z ? WoT : WiT;
    int c0 = blockIdx.x * 32, r0 = blockIdx.y * 32;
    for (int i = threadIdx.y; i < 32; i += 8)
        t[i][threadIdx.x] = in[(size_t)(r0 + i) * 1024 + c0 + threadIdx.x];
    __syncthreads();
    for (int i = threadIdx.y; i < 32; i += 8)
        out[(size_t)(c0 + i) * 1024 + r0 + threadIdx.x] = f2h(t[threadIdx.x][i]);
}

// ---------------- f16 MFMA GEMM: C[M,N] fp32 = A[M,K] * BT[N,K]^T ----------------
// MODE 0: A = f16 array via global_load_lds; no epilogue (GEMM2).
// MODE 1: A = fp32 x, reg-staged + split to f16 (hi,lo) in LDS on the fly.
//         T14 async-split: next K-step's x-loads are issued right after the
//         stage barrier so their latency hides under the MFMA phase.
//         pkrtz split: hi = RTZ(x), lo = RTZ(x - hi) — self-correcting to
//         ~2^-22 relative; epilogue C = K2LE*(acc + bi + hs*u + w)  (GEMM1).
// Both: XCD-chunked blockIdx swizzle (grid % 8 == 0).
// NOTE (R12 lesson): do NOT stage A as raw fp32 + split at fragment-read —
// fp32 fragments double the LDS-read bytes at 256B row stride (bank conflicts
// 1.9e7 -> 3.6e7, MfmaUtil 27 -> 22%, gemm1 107 -> 126 µs).
template<int MODE>
__global__ __launch_bounds__(256) void gemm_h(const unsigned short* __restrict__ Ah16,
                                              const float* __restrict__ Af32,
                                              const unsigned short* __restrict__ BT,
                                              float* __restrict__ C, int N, int K,
                                              const float* __restrict__ bi,
                                              const float* __restrict__ u,
                                              const float* __restrict__ hs,
                                              const float* __restrict__ wv) {
    constexpr int BM = 128, BN = 128, BK = 64;
    __shared__ alignas(16) unsigned short Ash[BM * BK];
    __shared__ alignas(16) unsigned short Asl[MODE ? BM * BK : 1];
    __shared__ alignas(16) unsigned short Bs[BN * BK];
    const int nb = N >> 7;
    // T1: XCD-chunked swizzle — consecutive logical tiles land on the same XCD L2.
    const int cpx = (int)gridDim.x >> 3;
    const int wg = (blockIdx.x & 7) * cpx + (blockIdx.x >> 3);
    const int bm = wg / nb, bn = wg % nb;
    const int tid = threadIdx.x;
    const int w = tid >> 6, l = tid & 63;
    const int wr = w >> 1, wc = w & 1;
    const int r = l & 15, g4 = l >> 4;
    const int lrow = l >> 3, lcol = (l & 7) * 8;

    f32x4 acc[4][4] = {};

    const size_t boff = (size_t)bn * BN * K;

    // MODE 1 prologue: first A-tile loads in flight before the loop.
    float4 av[8];
    if (MODE) {
#pragma unroll
        for (int i = 0; i < 8; i++) {
            int rg = (w * 8 + i) * 4 + (l >> 4);
            av[i] = *reinterpret_cast<const float4*>(
                Af32 + (size_t)(bm * BM + rg) * K + (l & 15) * 4);
        }
    }

    for (int k0 = 0; k0 < K; k0 += BK) {
        __syncthreads();
        // B staging: global_load_lds direct (unchanged).
#pragma unroll
        for (int i = 0; i < 4; i++) {
            size_t grow = (size_t)((w * 4 + i) * 8 + lrow) * K + (k0 + lcol);
            int ldst = (w * 4 + i) * 512;
            __builtin_amdgcn_global_load_lds(
                (const __attribute__((address_space(1))) void*)(BT + boff + grow),
                (__attribute__((address_space(3))) void*)(Bs + ldst), 16, 0, 0);
        }
        if (MODE) {
            // Convert current av (loaded last iteration) and stage to LDS.
#pragma unroll
            for (int i = 0; i < 8; i++) {
                int rg = (w * 8 + i) * 4 + (l >> 4);
                int off = rg * BK + (l & 15) * 4;
                float fx0 = av[i].x, fx1 = av[i].y, fx2 = av[i].z, fx3 = av[i].w;
                fp16x2 h01 = __builtin_amdgcn_cvt_pkrtz(fx0, fx1);
                fp16x2 h23 = __builtin_amdgcn_cvt_pkrtz(fx2, fx3);
                float r0 = fx0 - (float)h01[0];
                float r1 = fx1 - (float)h01[1];
                float r2 = fx2 - (float)h23[0];
                float r3 = fx3 - (float)h23[1];
                fp16x2 l01 = __builtin_amdgcn_cvt_pkrtz(r0, r1);
                fp16x2 l23 = __builtin_amdgcn_cvt_pkrtz(r2, r3);
                uint2 hh = { __builtin_bit_cast(unsigned int, h01),
                             __builtin_bit_cast(unsigned int, h23) };
                uint2 llv = { __builtin_bit_cast(unsigned int, l01),
                              __builtin_bit_cast(unsigned int, l23) };
                *reinterpret_cast<uint2*>(Ash + off) = hh;   // 128B/contiguous per 16 lanes
                *reinterpret_cast<uint2*>(Asl + off) = llv;
            }
        } else {
            const size_t aoff = (size_t)bm * BM * K;
#pragma unroll
            for (int i = 0; i < 4; i++) {
                size_t grow = (size_t)((w * 4 + i) * 8 + lrow) * K + (k0 + lcol);
                __builtin_amdgcn_global_load_lds(
                    (const __attribute__((address_space(1))) void*)(Ah16 + aoff + grow),
                    (__attribute__((address_space(3))) void*)(Ash + (w * 4 + i) * 512), 16, 0, 0);
            }
        }
        __syncthreads();
        // T14: issue NEXT K-step's A-loads now — latency hides under the MFMA
        // phase below (the conservative vmcnt(0) at the next barrier lands
        // after this cover). WAR on av is ordered by program order above.
        if (MODE && k0 + BK < K) {
#pragma unroll
            for (int i = 0; i < 8; i++) {
                int rg = (w * 8 + i) * 4 + (l >> 4);
                av[i] = *reinterpret_cast<const float4*>(
                    Af32 + (size_t)(bm * BM + rg) * K + (k0 + BK) + (l & 15) * 4);
            }
        }
#pragma unroll
        for (int kk = 0; kk < BK; kk += 32) {
            f16x8 ah[4], al[4], bf[4];
#pragma unroll
            for (int m = 0; m < 4; m++) {
                int off = (wr * 64 + m * 16 + r) * BK + kk + g4 * 8;
                ah[m] = *reinterpret_cast<const f16x8*>(Ash + off);
                if (MODE) al[m] = *reinterpret_cast<const f16x8*>(Asl + off);
            }
#pragma unroll
            for (int n = 0; n < 4; n++)
                bf[n] = *reinterpret_cast<const f16x8*>(Bs + (wc * 64 + n * 16 + r) * BK + kk + g4 * 8);
#pragma unroll
            for (int m = 0; m < 4; m++)
#pragma unroll
                for (int n = 0; n < 4; n++) {
                    acc[m][n] = __builtin_amdgcn_mfma_f32_16x16x32_f16(ah[m], bf[n], acc[m][n], 0, 0, 0);
                    if (MODE)
                        acc[m][n] = __builtin_amdgcn_mfma_f32_16x16x32_f16(al[m], bf[n], acc[m][n], 0, 0, 0);
                }
        }
    }

    const int bbase = MODE ? ((bm * BM) / Sc) * Nc : 0;   // batch uniform per block
#pragma unroll
    for (int m = 0; m < 4; m++) {
        int row = bm * BM + wr * 64 + m * 16 + g4 * 4;
#pragma unroll
        for (int n = 0; n < 4; n++) {
            int col = bn * BN + wc * 64 + n * 16 + r;
            float extra = 0.f;
            if (MODE) extra = bi[col] + hs[bbase + col] * u[col] + wv[col];
#pragma unroll
            for (int q = 0; q < 4; q++) {
                float v = acc[m][n][q];
                if (MODE) v = (v + extra) * K2LE;
                C[(size_t)(row + q) * N + col] = v;
            }
        }
    }
}

// ---------------- sequential tanh recurrence: producer-consumer waves ----------------
// PROVEN (round 5/8: 100 µs, absmax 0.07421875). Scan wall-time = S x chain
// latency (fma->v_exp->add->v_rcp ~52-58 cy) — a serial floor; parallelism
// cannot reduce it (round 6/7 lessons). Wave 0 (producer): per step
// z = fma(nw2, rr, x); e = exp2(z); rr = rcp(e+1); ds_write_b32 rr.
// Wave 1 (consumer): per 32-step chunk, reads rr from LDS, h = 1-2rr, packs
// f16, coalesced dwordx4 stores. Double-buffered LDS; lgkmcnt-only fence on
// wave 0 so the x-prefetch VMEM queue is NEVER drained.
static constexpr int SROW = 68;   // floats per LDS row (64 + 4 pad, 16B-aligned)

template<bool PREF>
__device__ __forceinline__ void sblk(const float* __restrict__ xrow,
                                     float (&cur)[32], float (&nxt)[32],
                                     float* __restrict__ hbl, int tblk, float nw2, float& rr) {
#pragma unroll
    for (int d = 0; d < 32; d++) {
        if (PREF) nxt[d] = xrow[(size_t)(tblk + 32 + d) << 10];   // 1 chunk ahead
        float z = fmaf(nw2, rr, cur[d]);
        float e = __ocml_native_exp2_f32(z);          // v_exp_f32
        rr = __builtin_amdgcn_rcpf(e + 1.f);          // v_rcp_f32
        hbl[d * SROW] = rr;                            // ds_write_b32, imm offset
    }
    asm volatile("s_waitcnt lgkmcnt(0)" ::: "memory");
    __builtin_amdgcn_s_barrier();
}

__device__ __forceinline__ unsigned int pk2(float a, float b) {
    return ((unsigned int)f2h(fmaf(-2.f, b, 1.f)) << 16) | f2h(fmaf(-2.f, a, 1.f));
}

__device__ __forceinline__ void drain(const float* __restrict__ buf, int tblk,
                                      unsigned short* __restrict__ srow, int n0, int l) {
    __builtin_amdgcn_s_barrier();
    asm volatile("" ::: "memory");
    int row8 = l >> 3, cg = l & 7;
#pragma unroll
    for (int i = 0; i < 4; i++) {
        int row = i * 8 + row8;
        float4 a = *reinterpret_cast<const float4*>(&buf[row * SROW + cg * 8]);
        float4 b = *reinterpret_cast<const float4*>(&buf[row * SROW + cg * 8 + 4]);
        uint4 v = { pk2(a.x, a.y), pk2(a.z, a.w), pk2(b.x, b.y), pk2(b.z, b.w) };
        *reinterpret_cast<uint4*>(&srow[((size_t)(tblk + row) << 10) + n0 + cg * 8]) = v;
    }
}

__global__ __launch_bounds__(128) void scan4(const float* __restrict__ xp,
                                             const float* __restrict__ w,
                                             const float* __restrict__ h0,
                                             unsigned short* __restrict__ states,
                                             float* __restrict__ out_state) {
    __shared__ alignas(16) float hb[2][32 * SROW];     // 17 KiB
    const int l = threadIdx.x & 63;
    const int wave = threadIdx.x >> 6;
    const int b = blockIdx.x >> 4;
    const int n0 = (blockIdx.x & 15) * 64;

    if (wave == 0) {
        const int tid = blockIdx.x * 64 + l;           // b*1024 + n
        const int n = tid & (Nc - 1);
        float nw2 = w[n] * (-2.f * K2LE);
        float rr = 0.5f - 0.5f * h0[tid];              // h = 1 - 2*rr
        const float* xrow = xp + ((size_t)b << 22) + n;
        float* hbl0 = &hb[0][l];
        float* hbl1 = &hb[1][l];

        float xa[32], xb[32];
#pragma unroll
        for (int d = 0; d < 32; d++) xa[d] = xrow[(size_t)d << 10];

        int t = 0;
        for (; t + 64 < Sc; t += 64) {
            sblk<true>(xrow, xa, xb, hbl0, t, nw2, rr);
            sblk<true>(xrow, xb, xa, hbl1, t + 32, nw2, rr);
        }
        sblk<true >(xrow, xa, xb, hbl0, t, nw2, rr);
        sblk<false>(xrow, xb, xa, hbl1, t + 32, nw2, rr);
        out_state[tid] = fmaf(-2.f, rr, 1.f);
    } else {
        unsigned short* srow = states + ((size_t)b << 22);
        for (int t = 0; t < Sc; t += 64) {
            drain(hb[0], t, srow, n0, l);
            drain(hb[1], t + 32, srow, n0, l);
        }
    }
}

extern "C" void kernel_launch(void* const* d_in, const int* in_sizes, int n_in,
                              void* d_out, int out_size, void* d_ws, size_t ws_size,
                              hipStream_t stream) {
    const float* x  = (const float*)d_in[0];
    const float* Wi = (const float*)d_in[1];
    const float* bi = (const float*)d_in[2];
    const float* w  = (const float*)d_in[3];
    const float* u  = (const float*)d_in[4];
    const float* Wo = (const float*)d_in[5];
    const float* h0 = (const float*)d_in[6];
    const float* hs = (const float*)d_in[7];
    float* out = (float*)d_out;                          // [M, OUT] fp32
    float* out_state = out + (size_t)Mc * OUTc;          // [B, N] fp32
    float* xp = out;                                     // xp scratch lives in d_out (dead before GEMM2)

    // ws layout (36 MiB): states (f16) 32M | WiT 2M | WoT 2M
    char* ws = (char*)d_ws;
    unsigned short* states = (unsigned short*)ws;
    unsigned short* WiT = (unsigned short*)(ws + 33554432);
    unsigned short* WoT = (unsigned short*)(ws + 35651584);

    tr_h2<<<dim3(32, 32, 2), dim3(32, 8), 0, stream>>>(Wi, Wo, WiT, WoT);

    gemm_h<1><<<(Mc / 128) * (Nc / 128), 256, 0, stream>>>(nullptr, x, WiT, xp, Nc, INc, bi, u, hs, w);
    scan4<<<64, 128, 0, stream>>>(xp, w, h0, states, out_state);
    gemm_h<0><<<(Mc / 128) * (OUTc / 128), 256, 0, stream>>>(states, nullptr, WoT, out, OUTc, Nc,
                                                             nullptr, nullptr, nullptr, nullptr);
}